// Round 7
// baseline (70.452 us; speedup 1.0000x reference)
//
#include <hip/hip_runtime.h>
#include <hip/hip_bf16.h>
#include <math.h>

#define NTOK 4096
#define CDIM 256
#define NH   8
#define HD   32
#define SCALE 0.17677669529663687f  // 32^-0.5

typedef __attribute__((ext_vector_type(8))) short bf16x8;
typedef __attribute__((ext_vector_type(4))) short short4v;
typedef __attribute__((ext_vector_type(4))) float f32x4;

__device__ inline short f2b(float f) {
  union { __hip_bfloat16 h; short s; } u;
  u.h = __float2bfloat16(f);
  return u.s;
}
__device__ inline short4v pack4(f32x4 v) {
  short4v o; o[0] = f2b(v[0]); o[1] = f2b(v[1]); o[2] = f2b(v[2]); o[3] = f2b(v[3]);
  return o;
}

// ---------------- prep_w: weight transposes to bf16 (tiny) ----------------
// WT[768][256] = {SCALE*Wq^T | Wk^T | Wv^T}, WpT[256][256] = Wproj^T
__global__ __launch_bounds__(256) void prep_w(
    const float* __restrict__ Wq, const float* __restrict__ Wkv,
    const float* __restrict__ Wp,
    short* __restrict__ WT, short* __restrict__ WpT)
{
  const int gid = blockIdx.x * 256 + threadIdx.x;   // 0..65535
  const int c  = gid & 1023;              // output row (transposed col)
  const int k4 = (gid >> 10) * 4;         // 0..252
  short4v o;
  if (c < 768) {
    #pragma unroll
    for (int j = 0; j < 4; ++j) {
      int k = k4 + j;
      float v = (c < 256) ? Wq[(size_t)k * 256 + c] * SCALE
                          : Wkv[(size_t)k * 512 + (c - 256)];
      o[j] = f2b(v);
    }
    *(short4v*)(WT + (size_t)c * 256 + k4) = o;
  } else {
    const int cc = c - 768;
    #pragma unroll
    for (int j = 0; j < 4; ++j) o[j] = f2b(Wp[(size_t)(k4 + j) * 256 + cc]);
    *(short4v*)(WpT + (size_t)cc * 256 + k4) = o;
  }
}

// ---------------- fused QKV projection (MFMA, inline f32->bf16 A) ----------------
// bx 0..3: q ((qkv+q_pos), swapped -> qb[n][c]); bx 4..7: k -> kb[n][c];
// bx 8..11: v (normal -> vT[c][n])
__global__ __launch_bounds__(256) void gemm_qkv(
    const float* __restrict__ qkv, const float* __restrict__ qpos,
    const short* __restrict__ WT,
    short* __restrict__ qb, short* __restrict__ kb, short* __restrict__ vTb)
{
  __shared__ short Al[64][40];
  __shared__ short Wl[64][40];
  const int bx = blockIdx.x;
  const int n0 = blockIdx.y * 64;
  const int c0 = bx * 64;                   // row range in WT [0,768)
  const int tid = threadIdx.x;
  const int w = tid >> 6, l = tid & 63, lg = l >> 4, lr = l & 15;
  const int wc = w & 1, wn = w >> 1;
  const bool useSum = (bx < 4);

  f32x4 acc[2][2];
  #pragma unroll
  for (int i = 0; i < 2; ++i)
    #pragma unroll
    for (int j = 0; j < 2; ++j) acc[i][j] = (f32x4){0.f, 0.f, 0.f, 0.f};

  for (int kt = 0; kt < 256; kt += 32) {
    __syncthreads();
    // A tile: 64 rows x 32 k, f32 -> bf16 inline (512 float4 chunks)
    #pragma unroll
    for (int it = 0; it < 2; ++it) {
      int ch = tid + it * 256;
      int row = ch >> 3, c4 = ch & 7;
      const float* src = qkv + (size_t)(n0 + row) * 256 + kt + c4 * 4;
      float4 a = *(const float4*)src;
      if (useSum) {
        float4 p = *(const float4*)(qpos + (size_t)(n0 + row) * 256 + kt + c4 * 4);
        a.x += p.x; a.y += p.y; a.z += p.z; a.w += p.w;
      }
      short4v s; s[0] = f2b(a.x); s[1] = f2b(a.y); s[2] = f2b(a.z); s[3] = f2b(a.w);
      *(short4v*)&Al[row][c4 * 4] = s;
    }
    // W tile: already bf16 (256 bf16x8 chunks)
    {
      int row = tid >> 2, seg = tid & 3;
      *(bf16x8*)&Wl[row][seg * 8] = *(const bf16x8*)(WT + (size_t)(c0 + row) * 256 + kt + seg * 8);
    }
    __syncthreads();
    bf16x8 wf[2], xf[2];
    #pragma unroll
    for (int ci = 0; ci < 2; ++ci) wf[ci] = *(bf16x8*)&Wl[wc * 32 + ci * 16 + lr][lg * 8];
    #pragma unroll
    for (int ni = 0; ni < 2; ++ni) xf[ni] = *(bf16x8*)&Al[wn * 32 + ni * 16 + lr][lg * 8];
    if (bx < 8) {
      #pragma unroll
      for (int ci = 0; ci < 2; ++ci)
        #pragma unroll
        for (int ni = 0; ni < 2; ++ni)
          acc[ci][ni] = __builtin_amdgcn_mfma_f32_16x16x32_bf16(wf[ci], xf[ni], acc[ci][ni], 0, 0, 0);
    } else {
      #pragma unroll
      for (int ci = 0; ci < 2; ++ci)
        #pragma unroll
        for (int ni = 0; ni < 2; ++ni)
          acc[ci][ni] = __builtin_amdgcn_mfma_f32_16x16x32_bf16(xf[ni], wf[ci], acc[ci][ni], 0, 0, 0);
    }
  }

  if (bx < 8) {
    short* dst = (bx < 4) ? qb : kb;
    const int cl0 = (bx & 3) * 64;
    #pragma unroll
    for (int ci = 0; ci < 2; ++ci)
      #pragma unroll
      for (int ni = 0; ni < 2; ++ni) {
        int c = cl0 + wc * 32 + ci * 16 + lg * 4;
        int n = n0 + wn * 32 + ni * 16 + lr;
        *(short4v*)(dst + (size_t)n * 256 + c) = pack4(acc[ci][ni]);
      }
  } else {
    const int cv0 = (bx - 8) * 64;
    #pragma unroll
    for (int ci = 0; ci < 2; ++ci)
      #pragma unroll
      for (int ni = 0; ni < 2; ++ni) {
        int c = cv0 + wc * 32 + ci * 16 + lr;
        int n = n0 + wn * 32 + ni * 16 + lg * 4;
        *(short4v*)(vTb + (size_t)c * NTOK + n) = pack4(acc[ci][ni]);
      }
  }
}

// ---------------- attn5: attn4 + bijective XCD swizzle ----------------
// Each XCD gets a contiguous 256-logical-block chunk (32 q-tiles x 8 heads)
// -> per-XCD K/V working set fits its 4 MiB L2.
__global__ __launch_bounds__(256) void attn5(
    const short* __restrict__ qb, const short* __restrict__ kbuf,
    const short* __restrict__ vT, const int* __restrict__ cu,
    short* __restrict__ featb)
{
  __shared__ float red[4][64][9];
  const int tid = threadIdx.x;
  const int w = tid >> 6, l = tid & 63, lg = l >> 4, lr = l & 15;
  const int bid = blockIdx.x;                       // 2048 blocks (8 | 2048)
  const int lid = ((bid & 7) << 8) | (bid >> 3);    // bijective XCD swizzle
  const int h = lid & 7, t = lid >> 3;
  const int n0 = t * 16;

  int cs[9];
  #pragma unroll
  for (int i = 0; i < 9; ++i) cs[i] = cu[i];

  const int qn = n0 + lr;                   // this lane's query (for masking)
  int sg = 0, sg0 = 0, sgL = 0;
  #pragma unroll
  for (int j = 1; j <= 8; ++j) {
    sg  += (cs[j] <= qn);
    sg0 += (cs[j] <= n0);
    sgL += (cs[j] <= n0 + 15);
  }
  const int kbegL = cs[sg], kendL = cs[sg + 1];
  const int lo = cs[sg0] & ~31;             // 32-aligned union start
  const int hi = cs[sgL + 1];
  const int nT = (hi - lo + 31) >> 5;       // 32-key tiles
  const int qT = (nT + 3) >> 2;
  const int it0 = w * qT;
  const int it1 = (it0 + qT < nT) ? (it0 + qT) : nT;

  const bf16x8 qf = *(const bf16x8*)(qb + (size_t)qn * 256 + h * 32 + lg * 8);
  const int kperm = (lr >> 2) * 8 + (lr & 3);           // row lr <-> key 8a+r
  const short* kP  = kbuf + h * 32 + lg * 8;            // + key*256
  const short* vP0 = vT + (size_t)(h * 32 + lr) * NTOK;       // d = lr
  const short* vP1 = vT + (size_t)(h * 32 + 16 + lr) * NTOK;  // d = 16+lr

  f32x4 acc0 = {0.f, 0.f, 0.f, 0.f}, acc1 = {0.f, 0.f, 0.f, 0.f};
  float Lp = 0.f;
  const f32x4 z4 = {0.f, 0.f, 0.f, 0.f};

  if (it0 < it1) {
    int tb = lo + it0 * 32;
    bf16x8 ka = *(const bf16x8*)(kP + (size_t)(tb + kperm) * 256);
    bf16x8 kc = *(const bf16x8*)(kP + (size_t)(tb + kperm + 4) * 256);
    bf16x8 va = *(const bf16x8*)(vP0 + tb + lg * 8);
    bf16x8 vb = *(const bf16x8*)(vP1 + tb + lg * 8);
    for (int it = it0; it < it1; ++it) {
      const int tn = lo + ((it + 1 < it1) ? (it + 1) : it) * 32;
      bf16x8 kna = *(const bf16x8*)(kP + (size_t)(tn + kperm) * 256);
      bf16x8 knc = *(const bf16x8*)(kP + (size_t)(tn + kperm + 4) * 256);
      bf16x8 vna = *(const bf16x8*)(vP0 + tn + lg * 8);
      bf16x8 vnb = *(const bf16x8*)(vP1 + tn + lg * 8);

      // swapped QK: s0[r] = S[key=tb+lg*8+r][q=lr], s1[r] = +4
      f32x4 s0 = __builtin_amdgcn_mfma_f32_16x16x32_bf16(ka, qf, z4, 0, 0, 0);
      f32x4 s1 = __builtin_amdgcn_mfma_f32_16x16x32_bf16(kc, qf, z4, 0, 0, 0);

      const int kgb = tb + lg * 8;
      bf16x8 pf;
      #pragma unroll
      for (int r = 0; r < 4; ++r) {
        int k0 = kgb + r;
        bool ok0 = (k0 >= kbegL) & (k0 < kendL);
        float p0 = ok0 ? __expf(s0[r]) : 0.f;
        int k1 = kgb + 4 + r;
        bool ok1 = (k1 >= kbegL) & (k1 < kendL);
        float p1 = ok1 ? __expf(s1[r]) : 0.f;
        Lp += p0 + p1;
        pf[r]     = f2b(p0);
        pf[4 + r] = f2b(p1);
      }
      // PV: lane's pf is P[q=lr][keys kgb..kgb+7] = exact A-fragment
      acc0 = __builtin_amdgcn_mfma_f32_16x16x32_bf16(pf, va, acc0, 0, 0, 0);
      acc1 = __builtin_amdgcn_mfma_f32_16x16x32_bf16(pf, vb, acc1, 0, 0, 0);

      ka = kna; kc = knc; va = vna; vb = vnb;
      tb = tn;
    }
  }

  // merge the 4 key-splits: pure sum (fixed-max softmax)
  #pragma unroll
  for (int r = 0; r < 4; ++r) { red[w][l][r] = acc0[r]; red[w][l][4 + r] = acc1[r]; }
  red[w][l][8] = Lp;
  __syncthreads();
  if (w == 0) {
    float a0[4] = {0.f, 0.f, 0.f, 0.f}, a1[4] = {0.f, 0.f, 0.f, 0.f}, Ls = 0.f;
    #pragma unroll
    for (int wv = 0; wv < 4; ++wv) {
      #pragma unroll
      for (int r = 0; r < 4; ++r) { a0[r] += red[wv][l][r]; a1[r] += red[wv][l][4 + r]; }
      Ls += red[wv][l][8];
    }
    // L lives at q=lr, spread over the 4 lg groups: butterfly then invert
    Ls += __shfl_xor(Ls, 16);
    Ls += __shfl_xor(Ls, 32);
    float inv = 1.f / Ls;                    // valid for q = n0 + lr
    #pragma unroll
    for (int r = 0; r < 4; ++r) {
      float iq = __shfl(inv, lg * 4 + r);    // lane lg*4+r (<16) has q=lg*4+r
      int n = n0 + lg * 4 + r;
      featb[(size_t)n * 256 + h * 32 + lr]      = f2b(a0[r] * iq);
      featb[(size_t)n * 256 + h * 32 + 16 + lr] = f2b(a1[r] * iq);
    }
  }
}

// ---------------- output projection (MFMA, 64x64 tiles, swapped) + bias ----------------
__global__ __launch_bounds__(256) void gemm_out(
    const short* __restrict__ Fb, const short* __restrict__ WpT,
    const float* __restrict__ bias, float* __restrict__ out)
{
  __shared__ short Al[64][40];
  __shared__ short Wl[64][40];
  const int c0 = blockIdx.x * 64;
  const int n0 = blockIdx.y * 64;
  const int tid = threadIdx.x;
  const int w = tid >> 6, l = tid & 63, lg = l >> 4, lr = l & 15;
  const int wc = w & 1, wn = w >> 1;

  f32x4 acc[2][2];
  #pragma unroll
  for (int i = 0; i < 2; ++i)
    #pragma unroll
    for (int j = 0; j < 2; ++j) acc[i][j] = (f32x4){0.f, 0.f, 0.f, 0.f};

  for (int kt = 0; kt < 256; kt += 32) {
    __syncthreads();
    {
      int row = tid >> 2, seg = tid & 3;
      *(bf16x8*)&Al[row][seg * 8] = *(const bf16x8*)(Fb  + (size_t)(n0 + row) * 256 + kt + seg * 8);
      *(bf16x8*)&Wl[row][seg * 8] = *(const bf16x8*)(WpT + (size_t)(c0 + row) * 256 + kt + seg * 8);
    }
    __syncthreads();
    bf16x8 wf[2], xf[2];
    #pragma unroll
    for (int ci = 0; ci < 2; ++ci) wf[ci] = *(bf16x8*)&Wl[wc * 32 + ci * 16 + lr][lg * 8];
    #pragma unroll
    for (int ni = 0; ni < 2; ++ni) xf[ni] = *(bf16x8*)&Al[wn * 32 + ni * 16 + lr][lg * 8];
    #pragma unroll
    for (int ci = 0; ci < 2; ++ci)
      #pragma unroll
      for (int ni = 0; ni < 2; ++ni)
        acc[ci][ni] = __builtin_amdgcn_mfma_f32_16x16x32_bf16(wf[ci], xf[ni], acc[ci][ni], 0, 0, 0);
  }

  #pragma unroll
  for (int ci = 0; ci < 2; ++ci)
    #pragma unroll
    for (int ni = 0; ni < 2; ++ni) {
      int c = c0 + wc * 32 + ci * 16 + lg * 4;
      int n = n0 + wn * 32 + ni * 16 + lr;
      f32x4 bv = *(const f32x4*)(bias + c);
      f32x4 o = acc[ci][ni] + bv;
      *(f32x4*)(out + (size_t)n * 256 + c) = o;
    }
}

extern "C" void kernel_launch(void* const* d_in, const int* in_sizes, int n_in,
                              void* d_out, int out_size, void* d_ws, size_t ws_size,
                              hipStream_t stream) {
  (void)in_sizes; (void)n_in; (void)out_size; (void)ws_size;
  const float* qkv   = (const float*)d_in[0];
  const float* q_pos = (const float*)d_in[1];
  const int*   cu    = (const int*)d_in[2];
  const float* Wq    = (const float*)d_in[4];
  const float* Wkv   = (const float*)d_in[5];
  const float* Wproj = (const float*)d_in[6];
  const float* bproj = (const float*)d_in[7];
  float* out = (float*)d_out;

  const size_t M = (size_t)NTOK * CDIM;   // 1048576
  short* S    = (short*)d_ws;
  short* qb   = S + 2 * M;
  short* kb   = S + 3 * M;
  short* vTb  = S + 4 * M;
  short* Fb   = S + 5 * M;
  short* WT   = S + 6 * M;
  short* WpT  = WT + 768 * 256;

  prep_w<<<256, 256, 0, stream>>>(Wq, Wkv, Wproj, WT, WpT);
  gemm_qkv<<<dim3(12, 64), 256, 0, stream>>>(qkv, q_pos, WT, qb, kb, vTb);
  attn5<<<2048, 256, 0, stream>>>(qb, kb, vTb, cu, Fb);
  gemm_out<<<dim3(4, 64), 256, 0, stream>>>(Fb, WpT, bproj, out);
}

// Round 8
// 44.901 us; speedup vs baseline: 1.5690x; 1.5690x over previous
//
#include <hip/hip_runtime.h>
#include <hip/hip_bf16.h>
#include <math.h>

#define NTOK 4096
#define CDIM 256
#define NH   8
#define HD   32
#define SCALE 0.17677669529663687f  // 32^-0.5

typedef __attribute__((ext_vector_type(8))) short bf16x8;
typedef __attribute__((ext_vector_type(4))) short short4v;
typedef __attribute__((ext_vector_type(4))) float f32x4;

__device__ inline short f2b(float f) {
  union { __hip_bfloat16 h; short s; } u;
  u.h = __float2bfloat16(f);
  return u.s;
}
__device__ inline short4v pack4(f32x4 v) {
  short4v o; o[0] = f2b(v[0]); o[1] = f2b(v[1]); o[2] = f2b(v[2]); o[3] = f2b(v[3]);
  return o;
}

// ---------------- prep: bf16 conversions + weight transposes ----------------
__global__ __launch_bounds__(256) void prep_kernel(
    const float* __restrict__ qkv, const float* __restrict__ qpos,
    const float* __restrict__ Wq, const float* __restrict__ Wkv,
    const float* __restrict__ Wp,
    short* __restrict__ Xq, short* __restrict__ X,
    short* __restrict__ WT, short* __restrict__ WpT)
{
  const int b = blockIdx.x, t = threadIdx.x;
  if (b < 1024) {
    const int i4 = (b * 256 + t) * 4;
    float4 a = *(const float4*)(qkv + i4);
    float4 p = *(const float4*)(qpos + i4);
    short4v xo, qo;
    xo[0] = f2b(a.x); xo[1] = f2b(a.y); xo[2] = f2b(a.z); xo[3] = f2b(a.w);
    qo[0] = f2b(a.x + p.x); qo[1] = f2b(a.y + p.y); qo[2] = f2b(a.z + p.z); qo[3] = f2b(a.w + p.w);
    *(short4v*)(X + i4)  = xo;
    *(short4v*)(Xq + i4) = qo;
  } else {
    const int gid = (b - 1024) * 256 + t;   // 0..65535
    const int c  = gid & 1023;
    const int k4 = (gid >> 10) * 4;
    short4v o;
    if (c < 768) {
      #pragma unroll
      for (int j = 0; j < 4; ++j) {
        int k = k4 + j;
        float v = (c < 256) ? Wq[(size_t)k * 256 + c] * SCALE
                            : Wkv[(size_t)k * 512 + (c - 256)];
        o[j] = f2b(v);
      }
      *(short4v*)(WT + (size_t)c * 256 + k4) = o;
    } else {
      const int cc = c - 768;
      #pragma unroll
      for (int j = 0; j < 4; ++j) o[j] = f2b(Wp[(size_t)(k4 + j) * 256 + cc]);
      *(short4v*)(WpT + (size_t)cc * 256 + k4) = o;
    }
  }
}

// ---------------- fused QKV projection (MFMA, 64x64 tiles) ----------------
// bx 0..3: q -> qb[n][c] (swapped); bx 4..7: k -> khp[h][tile][slot][d]
// (per-tile key-permuted); bx 8..11: v -> vblk[h][tile][d][k] (tile-blocked)
__global__ __launch_bounds__(256) void gemm_qkv(
    const short* __restrict__ Xq, const short* __restrict__ X,
    const short* __restrict__ WT,
    short* __restrict__ qb, short* __restrict__ khp, short* __restrict__ vblk)
{
  __shared__ short Al[64][40];
  __shared__ short Wl[64][40];
  const int bx = blockIdx.x;
  const int n0 = blockIdx.y * 64;
  const int c0 = bx * 64;                   // row range in WT [0,768)
  const int tid = threadIdx.x;
  const int w = tid >> 6, l = tid & 63, lg = l >> 4, lr = l & 15;
  const int wc = w & 1, wn = w >> 1;
  const short* A = (bx < 4) ? Xq : X;

  f32x4 acc[2][2];
  #pragma unroll
  for (int i = 0; i < 2; ++i)
    #pragma unroll
    for (int j = 0; j < 2; ++j) acc[i][j] = (f32x4){0.f, 0.f, 0.f, 0.f};

  for (int kt = 0; kt < 256; kt += 32) {
    __syncthreads();
    {
      int row = tid >> 2, seg = tid & 3;
      *(bf16x8*)&Al[row][seg * 8] = *(const bf16x8*)(A  + (size_t)(n0 + row) * 256 + kt + seg * 8);
      *(bf16x8*)&Wl[row][seg * 8] = *(const bf16x8*)(WT + (size_t)(c0 + row) * 256 + kt + seg * 8);
    }
    __syncthreads();
    bf16x8 wf[2], xf[2];
    #pragma unroll
    for (int ci = 0; ci < 2; ++ci) wf[ci] = *(bf16x8*)&Wl[wc * 32 + ci * 16 + lr][lg * 8];
    #pragma unroll
    for (int ni = 0; ni < 2; ++ni) xf[ni] = *(bf16x8*)&Al[wn * 32 + ni * 16 + lr][lg * 8];
    if (bx < 8) {
      #pragma unroll
      for (int ci = 0; ci < 2; ++ci)
        #pragma unroll
        for (int ni = 0; ni < 2; ++ni)
          acc[ci][ni] = __builtin_amdgcn_mfma_f32_16x16x32_bf16(wf[ci], xf[ni], acc[ci][ni], 0, 0, 0);
    } else {
      #pragma unroll
      for (int ci = 0; ci < 2; ++ci)
        #pragma unroll
        for (int ni = 0; ni < 2; ++ni)
          acc[ci][ni] = __builtin_amdgcn_mfma_f32_16x16x32_bf16(xf[ni], wf[ci], acc[ci][ni], 0, 0, 0);
    }
  }

  if (bx < 4) {
    // q, swapped: D[c][n]; lane holds 4 consecutive c, one n
    const int cl0 = bx * 64;
    #pragma unroll
    for (int ci = 0; ci < 2; ++ci)
      #pragma unroll
      for (int ni = 0; ni < 2; ++ni) {
        int c = cl0 + wc * 32 + ci * 16 + lg * 4;
        int n = n0 + wn * 32 + ni * 16 + lr;
        *(short4v*)(qb + (size_t)n * 256 + c) = pack4(acc[ci][ni]);
      }
  } else if (bx < 8) {
    // k, swapped: 4 consecutive d, one n -> khp[h][tile][slot(n&31)][d..d+3]
    const int cl0 = (bx - 4) * 64;
    #pragma unroll
    for (int ci = 0; ci < 2; ++ci)
      #pragma unroll
      for (int ni = 0; ni < 2; ++ni) {
        int c = cl0 + wc * 32 + ci * 16 + lg * 4;
        int n = n0 + wn * 32 + ni * 16 + lr;
        int hh = c >> 5, d = c & 31;
        int tt = n >> 5, k = n & 31;
        int s = ((k >> 2) & 1) * 16 + (k >> 3) * 4 + (k & 3);
        *(short4v*)(khp + (((size_t)hh * 128 + tt) * 32 + s) * 32 + d) = pack4(acc[ci][ni]);
      }
  } else {
    // v, normal: 4 consecutive n, one c -> vblk[h][tile][d][k..k+3]
    const int cv0 = (bx - 8) * 64;
    #pragma unroll
    for (int ci = 0; ci < 2; ++ci)
      #pragma unroll
      for (int ni = 0; ni < 2; ++ni) {
        int c = cv0 + wc * 32 + ci * 16 + lr;
        int n = n0 + wn * 32 + ni * 16 + lg * 4;
        int hh = c >> 5, d = c & 31;
        int tt = n >> 5, k = n & 31;
        *(short4v*)(vblk + (((size_t)hh * 128 + tt) * 32 + d) * 32 + k) = pack4(acc[ci][ni]);
      }
  }
}

// ---------------- attn6: coalesced K/V layouts + 4-way key split ----------------
// block = (16-query tile, head) via bijective XCD swizzle. Per 32-key tile the
// wave issues 4 perfectly-contiguous 1KB loads (khp/vblk layouts). Swapped QK
// with permuted K slots puts P directly into the PV A-fragment. Fixed-max
// softmax -> split merge is a pure sum.
__global__ __launch_bounds__(256) void attn6(
    const short* __restrict__ qb, const short* __restrict__ khp,
    const short* __restrict__ vblk, const int* __restrict__ cu,
    short* __restrict__ featb)
{
  __shared__ float red[4][64][9];
  const int tid = threadIdx.x;
  const int w = tid >> 6, l = tid & 63, lg = l >> 4, lr = l & 15;
  const int bid = blockIdx.x;                       // 2048 blocks (8 | 2048)
  const int lid = ((bid & 7) << 8) | (bid >> 3);    // bijective XCD swizzle
  const int h = lid & 7, t = lid >> 3;
  const int n0 = t * 16;

  int cs[9];
  #pragma unroll
  for (int i = 0; i < 9; ++i) cs[i] = cu[i];

  const int qn = n0 + lr;
  int sg = 0, sg0 = 0, sgL = 0;
  #pragma unroll
  for (int j = 1; j <= 8; ++j) {
    sg  += (cs[j] <= qn);
    sg0 += (cs[j] <= n0);
    sgL += (cs[j] <= n0 + 15);
  }
  const int kbegL = cs[sg], kendL = cs[sg + 1];
  const int lo = cs[sg0] & ~31;
  const int hi = cs[sgL + 1];
  const int t0 = lo >> 5;
  const int nT = (hi - lo + 31) >> 5;
  const int qT = (nT + 3) >> 2;
  const int it0 = w * qT;
  const int it1 = (it0 + qT < nT) ? (it0 + qT) : nT;

  const bf16x8 qf = *(const bf16x8*)(qb + (size_t)qn * 256 + h * 32 + lg * 8);
  // both K and V: lane offset l*16B within a 1KB tile block
  const short* kL = khp  + (size_t)h * 131072 + lr * 32 + lg * 8;
  const short* vL = vblk + (size_t)h * 131072 + lr * 32 + lg * 8;

  f32x4 acc0 = {0.f, 0.f, 0.f, 0.f}, acc1 = {0.f, 0.f, 0.f, 0.f};
  float Lp = 0.f;
  const f32x4 z4 = {0.f, 0.f, 0.f, 0.f};

  if (it0 < it1) {
    const short* kp = kL + (size_t)(t0 + it0) * 1024;
    const short* vp = vL + (size_t)(t0 + it0) * 1024;
    bf16x8 ka = *(const bf16x8*)(kp);
    bf16x8 kc = *(const bf16x8*)(kp + 512);
    bf16x8 va = *(const bf16x8*)(vp);
    bf16x8 vb = *(const bf16x8*)(vp + 512);
    for (int it = it0; it < it1; ++it) {
      const int itn = (it + 1 < it1) ? (it + 1) : it;
      const short* kpn = kL + (size_t)(t0 + itn) * 1024;
      const short* vpn = vL + (size_t)(t0 + itn) * 1024;
      bf16x8 kna = *(const bf16x8*)(kpn);
      bf16x8 knc = *(const bf16x8*)(kpn + 512);
      bf16x8 vna = *(const bf16x8*)(vpn);
      bf16x8 vnb = *(const bf16x8*)(vpn + 512);

      // swapped QK: s0[r] = S[key=tb+lg*8+r][q=lr], s1[r] = +4
      f32x4 s0 = __builtin_amdgcn_mfma_f32_16x16x32_bf16(ka, qf, z4, 0, 0, 0);
      f32x4 s1 = __builtin_amdgcn_mfma_f32_16x16x32_bf16(kc, qf, z4, 0, 0, 0);

      const int kgb = (t0 + it) * 32 + lg * 8;
      bf16x8 pf;
      #pragma unroll
      for (int r = 0; r < 4; ++r) {
        int k0 = kgb + r;
        bool ok0 = (k0 >= kbegL) & (k0 < kendL);
        float p0 = ok0 ? __expf(s0[r]) : 0.f;
        int k1 = kgb + 4 + r;
        bool ok1 = (k1 >= kbegL) & (k1 < kendL);
        float p1 = ok1 ? __expf(s1[r]) : 0.f;
        Lp += p0 + p1;
        pf[r]     = f2b(p0);
        pf[4 + r] = f2b(p1);
      }
      // PV: pf = P[q=lr][keys kgb..kgb+7] = exact A-fragment
      acc0 = __builtin_amdgcn_mfma_f32_16x16x32_bf16(pf, va, acc0, 0, 0, 0);
      acc1 = __builtin_amdgcn_mfma_f32_16x16x32_bf16(pf, vb, acc1, 0, 0, 0);

      ka = kna; kc = knc; va = vna; vb = vnb;
    }
  }

  // merge the 4 key-splits: pure sum (fixed-max softmax)
  #pragma unroll
  for (int r = 0; r < 4; ++r) { red[w][l][r] = acc0[r]; red[w][l][4 + r] = acc1[r]; }
  red[w][l][8] = Lp;
  __syncthreads();
  if (w == 0) {
    float a0[4] = {0.f, 0.f, 0.f, 0.f}, a1[4] = {0.f, 0.f, 0.f, 0.f}, Ls = 0.f;
    #pragma unroll
    for (int wv = 0; wv < 4; ++wv) {
      #pragma unroll
      for (int r = 0; r < 4; ++r) { a0[r] += red[wv][l][r]; a1[r] += red[wv][l][4 + r]; }
      Ls += red[wv][l][8];
    }
    Ls += __shfl_xor(Ls, 16);
    Ls += __shfl_xor(Ls, 32);
    float inv = 1.f / Ls;                    // valid for q = n0 + lr
    #pragma unroll
    for (int r = 0; r < 4; ++r) {
      float iq = __shfl(inv, lg * 4 + r);
      int n = n0 + lg * 4 + r;
      featb[(size_t)n * 256 + h * 32 + lr]      = f2b(a0[r] * iq);
      featb[(size_t)n * 256 + h * 32 + 16 + lr] = f2b(a1[r] * iq);
    }
  }
}

// ---------------- output projection (MFMA, 64x64 tiles, swapped) + bias ----------------
__global__ __launch_bounds__(256) void gemm_out(
    const short* __restrict__ Fb, const short* __restrict__ WpT,
    const float* __restrict__ bias, float* __restrict__ out)
{
  __shared__ short Al[64][40];
  __shared__ short Wl[64][40];
  const int c0 = blockIdx.x * 64;
  const int n0 = blockIdx.y * 64;
  const int tid = threadIdx.x;
  const int w = tid >> 6, l = tid & 63, lg = l >> 4, lr = l & 15;
  const int wc = w & 1, wn = w >> 1;

  f32x4 acc[2][2];
  #pragma unroll
  for (int i = 0; i < 2; ++i)
    #pragma unroll
    for (int j = 0; j < 2; ++j) acc[i][j] = (f32x4){0.f, 0.f, 0.f, 0.f};

  for (int kt = 0; kt < 256; kt += 32) {
    __syncthreads();
    {
      int row = tid >> 2, seg = tid & 3;
      *(bf16x8*)&Al[row][seg * 8] = *(const bf16x8*)(Fb  + (size_t)(n0 + row) * 256 + kt + seg * 8);
      *(bf16x8*)&Wl[row][seg * 8] = *(const bf16x8*)(WpT + (size_t)(c0 + row) * 256 + kt + seg * 8);
    }
    __syncthreads();
    bf16x8 wf[2], xf[2];
    #pragma unroll
    for (int ci = 0; ci < 2; ++ci) wf[ci] = *(bf16x8*)&Wl[wc * 32 + ci * 16 + lr][lg * 8];
    #pragma unroll
    for (int ni = 0; ni < 2; ++ni) xf[ni] = *(bf16x8*)&Al[wn * 32 + ni * 16 + lr][lg * 8];
    #pragma unroll
    for (int ci = 0; ci < 2; ++ci)
      #pragma unroll
      for (int ni = 0; ni < 2; ++ni)
        acc[ci][ni] = __builtin_amdgcn_mfma_f32_16x16x32_bf16(wf[ci], xf[ni], acc[ci][ni], 0, 0, 0);
  }

  #pragma unroll
  for (int ci = 0; ci < 2; ++ci)
    #pragma unroll
    for (int ni = 0; ni < 2; ++ni) {
      int c = c0 + wc * 32 + ci * 16 + lg * 4;
      int n = n0 + wn * 32 + ni * 16 + lr;
      f32x4 bv = *(const f32x4*)(bias + c);
      f32x4 o = acc[ci][ni] + bv;
      *(f32x4*)(out + (size_t)n * 256 + c) = o;
    }
}

extern "C" void kernel_launch(void* const* d_in, const int* in_sizes, int n_in,
                              void* d_out, int out_size, void* d_ws, size_t ws_size,
                              hipStream_t stream) {
  (void)in_sizes; (void)n_in; (void)out_size; (void)ws_size;
  const float* qkv   = (const float*)d_in[0];
  const float* q_pos = (const float*)d_in[1];
  const int*   cu    = (const int*)d_in[2];
  const float* Wq    = (const float*)d_in[4];
  const float* Wkv   = (const float*)d_in[5];
  const float* Wproj = (const float*)d_in[6];
  const float* bproj = (const float*)d_in[7];
  float* out = (float*)d_out;

  const size_t M = (size_t)NTOK * CDIM;   // 1048576
  short* S    = (short*)d_ws;
  short* Xq   = S;
  short* X    = S + M;
  short* qb   = S + 2 * M;
  short* khp  = S + 3 * M;
  short* vblk = S + 4 * M;
  short* Fb   = S + 5 * M;
  short* WT   = S + 6 * M;
  short* WpT  = WT + 768 * 256;

  prep_kernel<<<1280, 256, 0, stream>>>(qkv, q_pos, Wq, Wkv, Wproj, Xq, X, WT, WpT);
  gemm_qkv<<<dim3(12, 64), 256, 0, stream>>>(Xq, X, WT, qb, khp, vblk);
  attn6<<<2048, 256, 0, stream>>>(qb, khp, vblk, cu, Fb);
  gemm_out<<<dim3(4, 64), 256, 0, stream>>>(Fb, WpT, bproj, out);
}

// Round 9
// 39.478 us; speedup vs baseline: 1.7846x; 1.1374x over previous
//
#include <hip/hip_runtime.h>
#include <hip/hip_bf16.h>
#include <math.h>

#define NTOK 4096
#define CDIM 256
#define NH   8
#define HD   32
#define SCALE 0.17677669529663687f  // 32^-0.5

typedef __attribute__((ext_vector_type(8))) short bf16x8;
typedef __attribute__((ext_vector_type(4))) short short4v;
typedef __attribute__((ext_vector_type(4))) float f32x4;

__device__ inline short f2b(float f) {
  union { __hip_bfloat16 h; short s; } u;
  u.h = __float2bfloat16(f);
  return u.s;
}
__device__ inline short4v pack4(f32x4 v) {
  short4v o; o[0] = f2b(v[0]); o[1] = f2b(v[1]); o[2] = f2b(v[2]); o[3] = f2b(v[3]);
  return o;
}

// ---------------- prep: bf16 conversions + weight transposes ----------------
__global__ __launch_bounds__(256) void prep_kernel(
    const float* __restrict__ qkv, const float* __restrict__ qpos,
    const float* __restrict__ Wq, const float* __restrict__ Wkv,
    const float* __restrict__ Wp,
    short* __restrict__ Xq, short* __restrict__ X,
    short* __restrict__ WT, short* __restrict__ WpT)
{
  const int b = blockIdx.x, t = threadIdx.x;
  if (b < 1024) {
    const int i4 = (b * 256 + t) * 4;
    float4 a = *(const float4*)(qkv + i4);
    float4 p = *(const float4*)(qpos + i4);
    short4v xo, qo;
    xo[0] = f2b(a.x); xo[1] = f2b(a.y); xo[2] = f2b(a.z); xo[3] = f2b(a.w);
    qo[0] = f2b(a.x + p.x); qo[1] = f2b(a.y + p.y); qo[2] = f2b(a.z + p.z); qo[3] = f2b(a.w + p.w);
    *(short4v*)(X + i4)  = xo;
    *(short4v*)(Xq + i4) = qo;
  } else {
    const int gid = (b - 1024) * 256 + t;   // 0..65535
    const int c  = gid & 1023;
    const int k4 = (gid >> 10) * 4;
    short4v o;
    if (c < 768) {
      #pragma unroll
      for (int j = 0; j < 4; ++j) {
        int k = k4 + j;
        float v = (c < 256) ? Wq[(size_t)k * 256 + c] * SCALE
                            : Wkv[(size_t)k * 512 + (c - 256)];
        o[j] = f2b(v);
      }
      *(short4v*)(WT + (size_t)c * 256 + k4) = o;
    } else {
      const int cc = c - 768;
      #pragma unroll
      for (int j = 0; j < 4; ++j) o[j] = f2b(Wp[(size_t)(k4 + j) * 256 + cc]);
      *(short4v*)(WpT + (size_t)cc * 256 + k4) = o;
    }
  }
}

// ---------------- fused QKV projection (MFMA, 64x64 tiles) ----------------
// bx 0..3: q -> qb[n][c] (swapped); bx 4..7: k -> khp[h][tile][slot][d]
// (per-tile key-permuted); bx 8..11: v -> vblk[h][tile][d][k] (tile-blocked)
__global__ __launch_bounds__(256) void gemm_qkv(
    const short* __restrict__ Xq, const short* __restrict__ X,
    const short* __restrict__ WT,
    short* __restrict__ qb, short* __restrict__ khp, short* __restrict__ vblk)
{
  __shared__ short Al[64][40];
  __shared__ short Wl[64][40];
  const int bx = blockIdx.x;
  const int n0 = blockIdx.y * 64;
  const int c0 = bx * 64;                   // row range in WT [0,768)
  const int tid = threadIdx.x;
  const int w = tid >> 6, l = tid & 63, lg = l >> 4, lr = l & 15;
  const int wc = w & 1, wn = w >> 1;
  const short* A = (bx < 4) ? Xq : X;

  f32x4 acc[2][2];
  #pragma unroll
  for (int i = 0; i < 2; ++i)
    #pragma unroll
    for (int j = 0; j < 2; ++j) acc[i][j] = (f32x4){0.f, 0.f, 0.f, 0.f};

  for (int kt = 0; kt < 256; kt += 32) {
    __syncthreads();
    {
      int row = tid >> 2, seg = tid & 3;
      *(bf16x8*)&Al[row][seg * 8] = *(const bf16x8*)(A  + (size_t)(n0 + row) * 256 + kt + seg * 8);
      *(bf16x8*)&Wl[row][seg * 8] = *(const bf16x8*)(WT + (size_t)(c0 + row) * 256 + kt + seg * 8);
    }
    __syncthreads();
    bf16x8 wf[2], xf[2];
    #pragma unroll
    for (int ci = 0; ci < 2; ++ci) wf[ci] = *(bf16x8*)&Wl[wc * 32 + ci * 16 + lr][lg * 8];
    #pragma unroll
    for (int ni = 0; ni < 2; ++ni) xf[ni] = *(bf16x8*)&Al[wn * 32 + ni * 16 + lr][lg * 8];
    if (bx < 8) {
      #pragma unroll
      for (int ci = 0; ci < 2; ++ci)
        #pragma unroll
        for (int ni = 0; ni < 2; ++ni)
          acc[ci][ni] = __builtin_amdgcn_mfma_f32_16x16x32_bf16(wf[ci], xf[ni], acc[ci][ni], 0, 0, 0);
    } else {
      #pragma unroll
      for (int ci = 0; ci < 2; ++ci)
        #pragma unroll
        for (int ni = 0; ni < 2; ++ni)
          acc[ci][ni] = __builtin_amdgcn_mfma_f32_16x16x32_bf16(xf[ni], wf[ci], acc[ci][ni], 0, 0, 0);
    }
  }

  if (bx < 4) {
    const int cl0 = bx * 64;
    #pragma unroll
    for (int ci = 0; ci < 2; ++ci)
      #pragma unroll
      for (int ni = 0; ni < 2; ++ni) {
        int c = cl0 + wc * 32 + ci * 16 + lg * 4;
        int n = n0 + wn * 32 + ni * 16 + lr;
        *(short4v*)(qb + (size_t)n * 256 + c) = pack4(acc[ci][ni]);
      }
  } else if (bx < 8) {
    // k: khp[h][tile][slot][d], slot = ((k>>2)&1)*16 + (k>>3)*4 + (k&3)
    const int cl0 = (bx - 4) * 64;
    #pragma unroll
    for (int ci = 0; ci < 2; ++ci)
      #pragma unroll
      for (int ni = 0; ni < 2; ++ni) {
        int c = cl0 + wc * 32 + ci * 16 + lg * 4;
        int n = n0 + wn * 32 + ni * 16 + lr;
        int hh = c >> 5, d = c & 31;
        int tt = n >> 5, k = n & 31;
        int s = ((k >> 2) & 1) * 16 + (k >> 3) * 4 + (k & 3);
        *(short4v*)(khp + (((size_t)hh * 128 + tt) * 32 + s) * 32 + d) = pack4(acc[ci][ni]);
      }
  } else {
    // v: vblk[h][tile][d][k]
    const int cv0 = (bx - 8) * 64;
    #pragma unroll
    for (int ci = 0; ci < 2; ++ci)
      #pragma unroll
      for (int ni = 0; ni < 2; ++ni) {
        int c = cv0 + wc * 32 + ci * 16 + lr;
        int n = n0 + wn * 32 + ni * 16 + lg * 4;
        int hh = c >> 5, d = c & 31;
        int tt = n >> 5, k = n & 31;
        *(short4v*)(vblk + (((size_t)hh * 128 + tt) * 32 + d) * 32 + k) = pack4(acc[ci][ni]);
      }
  }
}

// ---------------- attn7: 32q/block + interior fast path + key split ----------------
// block = (32-query tile, head); 4 waves split the key range; each wave holds
// TWO Q fragments (q-rows n0..15 / 16..31): per 32-key tile 8 MFMAs on 4 loads.
// Interior tiles (fully inside the block's segment) skip all masking.
__global__ __launch_bounds__(256) void attn7(
    const short* __restrict__ qb, const short* __restrict__ khp,
    const short* __restrict__ vblk, const int* __restrict__ cu,
    short* __restrict__ featb)
{
  __shared__ float red[4][64][18];
  const int tid = threadIdx.x;
  const int w = tid >> 6, l = tid & 63, lg = l >> 4, lr = l & 15;
  const int bid = blockIdx.x;                       // 1024 blocks (8 | 1024)
  const int lid = ((bid & 7) << 7) | (bid >> 3);    // bijective XCD swizzle
  const int h = lid & 7, t32 = lid >> 3;
  const int n0 = t32 * 32;

  int cs[9];
  #pragma unroll
  for (int i = 0; i < 9; ++i) cs[i] = cu[i];

  const int qn0 = n0 + lr, qn1 = n0 + 16 + lr;
  int g0 = 0, g1 = 0, sg0 = 0, sgL = 0;
  #pragma unroll
  for (int j = 1; j <= 8; ++j) {
    g0  += (cs[j] <= qn0);
    g1  += (cs[j] <= qn1);
    sg0 += (cs[j] <= n0);
    sgL += (cs[j] <= n0 + 31);
  }
  const int kbeg0 = cs[g0], kend0 = cs[g0 + 1];
  const int kbeg1 = cs[g1], kend1 = cs[g1 + 1];
  const bool oneSeg = (sg0 == sgL);
  const int kbB = cs[sg0], keB = cs[sgL + 1];
  const int lo = kbB & ~31;
  const int hi = keB;
  const int t0 = lo >> 5;
  const int nT = (hi - lo + 31) >> 5;
  const int qT = (nT + 3) >> 2;
  const int it0 = w * qT;
  const int it1 = (it0 + qT < nT) ? (it0 + qT) : nT;

  const bf16x8 qf0 = *(const bf16x8*)(qb + (size_t)qn0 * 256 + h * 32 + lg * 8);
  const bf16x8 qf1 = *(const bf16x8*)(qb + (size_t)qn1 * 256 + h * 32 + lg * 8);
  const short* kL = khp  + (size_t)h * 131072 + lr * 32 + lg * 8;
  const short* vL = vblk + (size_t)h * 131072 + lr * 32 + lg * 8;

  f32x4 acc00 = {0.f,0.f,0.f,0.f}, acc01 = {0.f,0.f,0.f,0.f};
  f32x4 acc10 = {0.f,0.f,0.f,0.f}, acc11 = {0.f,0.f,0.f,0.f};
  float Lp0 = 0.f, Lp1 = 0.f;
  const f32x4 z4 = {0.f, 0.f, 0.f, 0.f};

  if (it0 < it1) {
    const short* kp = kL + (size_t)(t0 + it0) * 1024;
    const short* vp = vL + (size_t)(t0 + it0) * 1024;
    bf16x8 ka = *(const bf16x8*)(kp);
    bf16x8 kc = *(const bf16x8*)(kp + 512);
    bf16x8 va = *(const bf16x8*)(vp);
    bf16x8 vb = *(const bf16x8*)(vp + 512);
    for (int it = it0; it < it1; ++it) {
      const int itn = (it + 1 < it1) ? (it + 1) : it;
      const short* kpn = kL + (size_t)(t0 + itn) * 1024;
      const short* vpn = vL + (size_t)(t0 + itn) * 1024;
      bf16x8 kna = *(const bf16x8*)(kpn);
      bf16x8 knc = *(const bf16x8*)(kpn + 512);
      bf16x8 vna = *(const bf16x8*)(vpn);
      bf16x8 vnb = *(const bf16x8*)(vpn + 512);

      f32x4 s00 = __builtin_amdgcn_mfma_f32_16x16x32_bf16(ka, qf0, z4, 0, 0, 0);
      f32x4 s01 = __builtin_amdgcn_mfma_f32_16x16x32_bf16(kc, qf0, z4, 0, 0, 0);
      f32x4 s10 = __builtin_amdgcn_mfma_f32_16x16x32_bf16(ka, qf1, z4, 0, 0, 0);
      f32x4 s11 = __builtin_amdgcn_mfma_f32_16x16x32_bf16(kc, qf1, z4, 0, 0, 0);

      const int kt0 = (t0 + it) * 32;
      bf16x8 pf0, pf1;
      if (oneSeg & (kt0 >= kbB) & (kt0 + 32 <= keB)) {
        // interior tile: no masking
        #pragma unroll
        for (int r = 0; r < 4; ++r) {
          float p00 = __expf(s00[r]), p01 = __expf(s01[r]);
          float p10 = __expf(s10[r]), p11 = __expf(s11[r]);
          Lp0 += p00 + p01; Lp1 += p10 + p11;
          pf0[r] = f2b(p00); pf0[4 + r] = f2b(p01);
          pf1[r] = f2b(p10); pf1[4 + r] = f2b(p11);
        }
      } else {
        const int kgb = kt0 + lg * 8;
        #pragma unroll
        for (int r = 0; r < 4; ++r) {
          int k0 = kgb + r, k1 = kgb + 4 + r;
          bool a00 = (k0 >= kbeg0) & (k0 < kend0);
          bool a01 = (k1 >= kbeg0) & (k1 < kend0);
          bool a10 = (k0 >= kbeg1) & (k0 < kend1);
          bool a11 = (k1 >= kbeg1) & (k1 < kend1);
          float p00 = a00 ? __expf(s00[r]) : 0.f;
          float p01 = a01 ? __expf(s01[r]) : 0.f;
          float p10 = a10 ? __expf(s10[r]) : 0.f;
          float p11 = a11 ? __expf(s11[r]) : 0.f;
          Lp0 += p00 + p01; Lp1 += p10 + p11;
          pf0[r] = f2b(p00); pf0[4 + r] = f2b(p01);
          pf1[r] = f2b(p10); pf1[4 + r] = f2b(p11);
        }
      }
      acc00 = __builtin_amdgcn_mfma_f32_16x16x32_bf16(pf0, va, acc00, 0, 0, 0);
      acc01 = __builtin_amdgcn_mfma_f32_16x16x32_bf16(pf0, vb, acc01, 0, 0, 0);
      acc10 = __builtin_amdgcn_mfma_f32_16x16x32_bf16(pf1, va, acc10, 0, 0, 0);
      acc11 = __builtin_amdgcn_mfma_f32_16x16x32_bf16(pf1, vb, acc11, 0, 0, 0);

      ka = kna; kc = knc; va = vna; vb = vnb;
    }
  }

  // merge the 4 key-splits: pure sum (fixed-max softmax)
  #pragma unroll
  for (int r = 0; r < 4; ++r) {
    red[w][l][r]      = acc00[r];
    red[w][l][4 + r]  = acc01[r];
    red[w][l][8 + r]  = acc10[r];
    red[w][l][12 + r] = acc11[r];
  }
  red[w][l][16] = Lp0;
  red[w][l][17] = Lp1;
  __syncthreads();
  if (w == 0) {
    float a00[4] = {0,0,0,0}, a01[4] = {0,0,0,0};
    float a10[4] = {0,0,0,0}, a11[4] = {0,0,0,0};
    float Ls0 = 0.f, Ls1 = 0.f;
    #pragma unroll
    for (int wv = 0; wv < 4; ++wv) {
      #pragma unroll
      for (int r = 0; r < 4; ++r) {
        a00[r] += red[wv][l][r];      a01[r] += red[wv][l][4 + r];
        a10[r] += red[wv][l][8 + r];  a11[r] += red[wv][l][12 + r];
      }
      Ls0 += red[wv][l][16];
      Ls1 += red[wv][l][17];
    }
    Ls0 += __shfl_xor(Ls0, 16); Ls0 += __shfl_xor(Ls0, 32);
    Ls1 += __shfl_xor(Ls1, 16); Ls1 += __shfl_xor(Ls1, 32);
    float inv0 = 1.f / Ls0, inv1 = 1.f / Ls1;
    #pragma unroll
    for (int r = 0; r < 4; ++r) {
      float i0 = __shfl(inv0, lg * 4 + r);
      float i1 = __shfl(inv1, lg * 4 + r);
      int na = n0 + lg * 4 + r;
      int nb = n0 + 16 + lg * 4 + r;
      featb[(size_t)na * 256 + h * 32 + lr]      = f2b(a00[r] * i0);
      featb[(size_t)na * 256 + h * 32 + 16 + lr] = f2b(a01[r] * i0);
      featb[(size_t)nb * 256 + h * 32 + lr]      = f2b(a10[r] * i1);
      featb[(size_t)nb * 256 + h * 32 + 16 + lr] = f2b(a11[r] * i1);
    }
  }
}

// ---------------- output projection (MFMA, 64x64 tiles, swapped) + bias ----------------
__global__ __launch_bounds__(256) void gemm_out(
    const short* __restrict__ Fb, const short* __restrict__ WpT,
    const float* __restrict__ bias, float* __restrict__ out)
{
  __shared__ short Al[64][40];
  __shared__ short Wl[64][40];
  const int c0 = blockIdx.x * 64;
  const int n0 = blockIdx.y * 64;
  const int tid = threadIdx.x;
  const int w = tid >> 6, l = tid & 63, lg = l >> 4, lr = l & 15;
  const int wc = w & 1, wn = w >> 1;

  f32x4 acc[2][2];
  #pragma unroll
  for (int i = 0; i < 2; ++i)
    #pragma unroll
    for (int j = 0; j < 2; ++j) acc[i][j] = (f32x4){0.f, 0.f, 0.f, 0.f};

  for (int kt = 0; kt < 256; kt += 32) {
    __syncthreads();
    {
      int row = tid >> 2, seg = tid & 3;
      *(bf16x8*)&Al[row][seg * 8] = *(const bf16x8*)(Fb  + (size_t)(n0 + row) * 256 + kt + seg * 8);
      *(bf16x8*)&Wl[row][seg * 8] = *(const bf16x8*)(WpT + (size_t)(c0 + row) * 256 + kt + seg * 8);
    }
    __syncthreads();
    bf16x8 wf[2], xf[2];
    #pragma unroll
    for (int ci = 0; ci < 2; ++ci) wf[ci] = *(bf16x8*)&Wl[wc * 32 + ci * 16 + lr][lg * 8];
    #pragma unroll
    for (int ni = 0; ni < 2; ++ni) xf[ni] = *(bf16x8*)&Al[wn * 32 + ni * 16 + lr][lg * 8];
    #pragma unroll
    for (int ci = 0; ci < 2; ++ci)
      #pragma unroll
      for (int ni = 0; ni < 2; ++ni)
        acc[ci][ni] = __builtin_amdgcn_mfma_f32_16x16x32_bf16(wf[ci], xf[ni], acc[ci][ni], 0, 0, 0);
  }

  #pragma unroll
  for (int ci = 0; ci < 2; ++ci)
    #pragma unroll
    for (int ni = 0; ni < 2; ++ni) {
      int c = c0 + wc * 32 + ci * 16 + lg * 4;
      int n = n0 + wn * 32 + ni * 16 + lr;
      f32x4 bv = *(const f32x4*)(bias + c);
      f32x4 o = acc[ci][ni] + bv;
      *(f32x4*)(out + (size_t)n * 256 + c) = o;
    }
}

extern "C" void kernel_launch(void* const* d_in, const int* in_sizes, int n_in,
                              void* d_out, int out_size, void* d_ws, size_t ws_size,
                              hipStream_t stream) {
  (void)in_sizes; (void)n_in; (void)out_size; (void)ws_size;
  const float* qkv   = (const float*)d_in[0];
  const float* q_pos = (const float*)d_in[1];
  const int*   cu    = (const int*)d_in[2];
  const float* Wq    = (const float*)d_in[4];
  const float* Wkv   = (const float*)d_in[5];
  const float* Wproj = (const float*)d_in[6];
  const float* bproj = (const float*)d_in[7];
  float* out = (float*)d_out;

  const size_t M = (size_t)NTOK * CDIM;   // 1048576
  short* S    = (short*)d_ws;
  short* Xq   = S;
  short* X    = S + M;
  short* qb   = S + 2 * M;
  short* khp  = S + 3 * M;
  short* vblk = S + 4 * M;
  short* Fb   = S + 5 * M;
  short* WT   = S + 6 * M;
  short* WpT  = WT + 768 * 256;

  prep_kernel<<<1280, 256, 0, stream>>>(qkv, q_pos, Wq, Wkv, Wproj, Xq, X, WT, WpT);
  gemm_qkv<<<dim3(12, 64), 256, 0, stream>>>(Xq, X, WT, qb, khp, vblk);
  attn7<<<1024, 256, 0, stream>>>(qb, khp, vblk, cu, Fb);
  gemm_out<<<dim3(4, 64), 256, 0, stream>>>(Fb, WpT, bproj, out);
}